// Round 7
// baseline (16978.218 us; speedup 1.0000x reference)
//
#include <hip/hip_runtime.h>

#define HB 64      // batch
#define HT 1024    // time
#define HI 256     // input dim
#define HH 512     // hidden dim

typedef short short8 __attribute__((ext_vector_type(8)));
typedef float f32x4 __attribute__((ext_vector_type(4)));
typedef int   i32x4 __attribute__((ext_vector_type(4)));

__device__ __forceinline__ unsigned short f2bf(float f) {
    unsigned u = __float_as_uint(f);
    u += 0x7FFF + ((u >> 16) & 1);          // round-to-nearest-even
    return (unsigned short)(u >> 16);
}
__device__ __forceinline__ float bf2f(unsigned short s) {
    return __uint_as_float(((unsigned)s) << 16);
}
__device__ __forceinline__ float fsigmoid(float x) {
    return __builtin_amdgcn_rcpf(1.0f + __expf(-x));
}
__device__ __forceinline__ float ftanh(float x) {
    return 1.0f - 2.0f * __builtin_amdgcn_rcpf(__expf(2.0f * x) + 1.0f);
}

// Tagged 16B pair stores. loc = sc0 only (stays in XCD L2); mall = sc0 sc1.
__device__ __forceinline__ void st_pair_loc(void* p, i32x4 v) {
    asm volatile("global_store_dwordx4 %0, %1, off sc0" :: "v"(p), "v"(v) : "memory");
}
__device__ __forceinline__ void st_pair_mall(void* p, i32x4 v) {
    asm volatile("global_store_dwordx4 %0, %1, off sc0 sc1" :: "v"(p), "v"(v) : "memory");
}
__device__ __forceinline__ void lds_fence() {
    asm volatile("s_waitcnt lgkmcnt(0)" ::: "memory");
    __builtin_amdgcn_sched_barrier(0);
}
// Guarded MALL dword load: waitcnt + sched_barrier BEFORE any use (rule #18).
__device__ __forceinline__ int ld4m(const int* p) {
    int v;
    asm volatile("global_load_dword %0, %1, off sc0 sc1" : "=v"(v) : "v"(p) : "memory");
    asm volatile("s_waitcnt vmcnt(0)" ::: "memory");
    __builtin_amdgcn_sched_barrier(0);
    return v;
}

// ---------------------------------------------------------------------------
// Tag-validated pulls (round-3-proven layout): per lane 32 tagged 16B pairs =
// 16 fragments. kt stride 2048B, lane stride 32B, pair at +0/+16.
// LOCAL variant: sc0 loads + buffer_inv each attempt (L1-staleness shield —
// no-op if sc0 already bypasses L1). MALL variant: sc0 sc1 (proven).
// Fuel: on exhaustion accept data -> visible wrong answer, never a hang.
// ---------------------------------------------------------------------------
__device__ __forceinline__ void pull16_loc(const char* base0, int expect,
                                           short8* af, int& fuel) {
    for (;;) {
        asm volatile("buffer_inv" ::: "memory");
        i32x4 v[32];
        const char* b = base0;
        #pragma unroll
        for (int bi = 0; bi < 8; ++bi) {
            asm volatile("global_load_dwordx4 %0, %1, off sc0"
                         : "=v"(v[bi * 4 + 0]) : "v"(b));
            asm volatile("global_load_dwordx4 %0, %1, off offset:16 sc0"
                         : "=v"(v[bi * 4 + 1]) : "v"(b));
            asm volatile("global_load_dwordx4 %0, %1, off offset:2048 sc0"
                         : "=v"(v[bi * 4 + 2]) : "v"(b));
            asm volatile("global_load_dwordx4 %0, %1, off offset:2064 sc0"
                         : "=v"(v[bi * 4 + 3]) : "v"(b));
            b += 4096;
        }
        asm volatile("s_waitcnt vmcnt(0)" ::: "memory");
        __builtin_amdgcn_sched_barrier(0);
        int ok = 1;
        #pragma unroll
        for (int i = 0; i < 32; ++i)
            ok &= (v[i][2] == expect) & (v[i][3] == 0);
        bool done = (__ballot(ok != 0) == ~0ull);
        if (!done) {
            fuel -= 64;
            if (fuel > 0) { __builtin_amdgcn_s_sleep(2); continue; }
        }
        #pragma unroll
        for (int kt = 0; kt < 16; ++kt) {
            union { int i4[4]; short8 s; } u;
            u.i4[0] = v[2 * kt][0];     u.i4[1] = v[2 * kt][1];
            u.i4[2] = v[2 * kt + 1][0]; u.i4[3] = v[2 * kt + 1][1];
            af[kt] = u.s;
        }
        return;
    }
}
__device__ __forceinline__ void pull16_mall(const char* base0, int expect,
                                            short8* af, int& fuel) {
    for (;;) {
        i32x4 v[32];
        const char* b = base0;
        #pragma unroll
        for (int bi = 0; bi < 8; ++bi) {
            asm volatile("global_load_dwordx4 %0, %1, off sc0 sc1"
                         : "=v"(v[bi * 4 + 0]) : "v"(b));
            asm volatile("global_load_dwordx4 %0, %1, off offset:16 sc0 sc1"
                         : "=v"(v[bi * 4 + 1]) : "v"(b));
            asm volatile("global_load_dwordx4 %0, %1, off offset:2048 sc0 sc1"
                         : "=v"(v[bi * 4 + 2]) : "v"(b));
            asm volatile("global_load_dwordx4 %0, %1, off offset:2064 sc0 sc1"
                         : "=v"(v[bi * 4 + 3]) : "v"(b));
            b += 4096;
        }
        asm volatile("s_waitcnt vmcnt(0)" ::: "memory");
        __builtin_amdgcn_sched_barrier(0);
        int ok = 1;
        #pragma unroll
        for (int i = 0; i < 32; ++i)
            ok &= (v[i][2] == expect) & (v[i][3] == 0);
        bool done = (__ballot(ok != 0) == ~0ull);
        if (!done) {
            fuel -= 64;
            if (fuel > 0) { __builtin_amdgcn_s_sleep(2); continue; }
        }
        #pragma unroll
        for (int kt = 0; kt < 16; ++kt) {
            union { int i4[4]; short8 s; } u;
            u.i4[0] = v[2 * kt][0];     u.i4[1] = v[2 * kt][1];
            u.i4[2] = v[2 * kt + 1][0]; u.i4[3] = v[2 * kt + 1][1];
            af[kt] = u.s;
        }
        return;
    }
}

// ---------------------------------------------------------------------------
// Pack weights to bf16 in MFMA B-fragment-linear layout (proven round 1).
// ---------------------------------------------------------------------------
__global__ void pack_weights(const float* __restrict__ Wih0, const float* __restrict__ Whh0,
                             const float* __restrict__ bih0, const float* __restrict__ bhh0,
                             const float* __restrict__ Wih1, const float* __restrict__ Whh1,
                             const float* __restrict__ bih1, const float* __restrict__ bhh1,
                             unsigned short* __restrict__ wp0,
                             unsigned short* __restrict__ wp1,
                             float* __restrict__ bs) {
    int idx = blockIdx.x * 256 + threadIdx.x;
    int stride = gridDim.x * 256;
    const int NP0 = 128 * 24 * 512;
    const int NP1 = 128 * 32 * 512;
    for (int e = idx; e < NP0; e += stride) {
        int j = e & 7, l = (e >> 3) & 63, rem = e >> 9;
        int kt = rem % 24, nt = rem / 24;
        int n = nt * 16 + (l & 15);
        int k = kt * 32 + ((l >> 4) << 3) + j;
        float v = (k < HI) ? Wih0[n * HI + k] : Whh0[n * HH + (k - HI)];
        wp0[e] = f2bf(v);
    }
    for (int e = idx; e < NP1; e += stride) {
        int j = e & 7, l = (e >> 3) & 63, rem = e >> 9;
        int kt = rem & 31, nt = rem >> 5;
        int n = nt * 16 + (l & 15);
        int k = kt * 32 + ((l >> 4) << 3) + j;
        float v = (k < HH) ? Wih1[n * HH + k] : Whh1[n * HH + (k - HH)];
        wp1[e] = f2bf(v);
    }
    for (int e = idx; e < 2048; e += stride) {
        bs[e]        = bih0[e] + bhh0[e];
        bs[2048 + e] = bih1[e] + bhh1[e];
    }
}

// ---------------------------------------------------------------------------
// Pack x (B,1,I,T) -> bf16 A-fragment layout xp[t][mt(4)][kt(8)][lane(64)][j(8)]
// ---------------------------------------------------------------------------
__global__ void pack_x(const float* __restrict__ x, unsigned short* __restrict__ xp) {
    int tt = blockIdx.x;   // 64
    int ii = blockIdx.y;   // 8
    int bt = blockIdx.z;   // 4
    int w  = threadIdx.x;  // 256
    __shared__ unsigned short tile[512][16];
    int tloc = w & 15;
    for (int q = 0; q < 32; ++q) {
        int p = q * 16 + (w >> 4);
        int m = p >> 5, iloc = p & 31;
        int b = bt * 16 + m, i = ii * 32 + iloc, t = tt * 16 + tloc;
        tile[p][tloc] = f2bf(x[((size_t)b * HI + i) * HT + t]);
    }
    __syncthreads();
    int e  = w * 2;
    int l  = e >> 3, j0 = e & 7;
    int m  = l & 15;
    int i0 = ((l >> 4) << 3) + j0;
    for (int ti = 0; ti < 16; ++ti) {
        int t = tt * 16 + ti;
        size_t base = ((size_t)(t * 4 + bt) * 8 + ii) * 512;
        unsigned v0 = tile[m * 32 + i0][ti];
        unsigned v1 = tile[m * 32 + i0 + 1][ti];
        ((unsigned int*)xp)[(base + e) >> 1] = v0 | (v1 << 16);
    }
}

// Per launch: zero claim counters + f1m; bump run-base by 2048 so ring tags
// are RUN-UNIQUE (rb + t) — graph-replay residue in any cache level can
// never alias a current-run tag. Rings themselves are never re-initialized
// (only their producing XCD's L2 / MALL ever writes them).
__global__ void init_sync(int* __restrict__ s) {
    int i = threadIdx.x;
    if (i == 0) { s[0] = 0; s[1] = 0; s[2] += 2048; }
    if (i >= 64 && i < 192) s[i] = 0;   // f1m[128]
}

// ---------------------------------------------------------------------------
// Persistent LSTM — XCD-local, tag-synchronized, flag-free fast path.
// 256 blocks x 256 threads, 1 block/CU (LDS-forced) => exactly 32 blocks per
// XCD. Self-claim via HW_REG_XCC_ID: XCD0 -> layer0, XCD1 -> layer1, rest exit.
//  - h0loc/h1loc: depth-2 TAGGED rings, sc0 only => XCD-L2-resident exchange.
//    Tag validation IS the sync: seeing all peers' tag-(t-1) data proves all
//    peers completed their step-(t-2) reads (pull precedes store in program
//    order, pull's vmcnt(0) completes it) => depth-2 reuse is safe, NO flags,
//    NO drains, NO barriers. buffer_inv per attempt shields against sc0 L1
//    hits (no-op if sc0 bypasses L1).
//  - h0mall: depth-4 TAGGED ring, sc0 sc1 (MALL), feeds layer1. Readiness by
//    tags (layer0 runs ahead). Slot reuse gated by f1m (layer1 progress,
//    MALL flag): overwrite slot t&3 at step t needs f1m >= t-3. Gate is
//    early-issued; its use sits behind sched_barrier(0) AFTER the local
//    pull's vmcnt(0) -> load provably retired (in-order vmcnt), zero waits.
//  - rule #18 hardened: every inline-asm load's use is behind a
//    vmcnt + sched_barrier(0) pair in program order.
//  - fuel watchdogs: any protocol failure = visible wrong answer, not a hang.
// MFMA accumulation order identical to round-0 => absmax must be bit-exact
// (0.00390625) — the race canary.
// ---------------------------------------------------------------------------
__global__ void __launch_bounds__(256, 1) lstm_persist(
        const unsigned short* __restrict__ wp0,
        const unsigned short* __restrict__ wp1,
        const float* __restrict__ bs,
        const unsigned short* __restrict__ xp,
        char* __restrict__ h0loc,    // 2 slots x [mt4][kt16][lane64][pair2]x16B
        char* __restrict__ h1loc,    // 2 slots x same
        char* __restrict__ h0mall,   // 4 slots x same
        int* __restrict__ sync,      // [0,1]=claim cnt, [2]=rb, [64..191]=f1m
        float* __restrict__ out) {
    __shared__ int4 ldsw[8192];                 // 128 KB weight slice
    __shared__ unsigned short stage_s[1024];    // 2 KB h staging (wave-private)
    __shared__ int rs[2];

    int* f1m = sync + 64;
    const int tid = threadIdx.x;
    int xcd;
    asm volatile("s_getreg_b32 %0, hwreg(HW_REG_XCC_ID)" : "=s"(xcd));
    if (tid == 0) {
        int role = -1, slot = 0;
        if (xcd == 0) {
            slot = __hip_atomic_fetch_add(sync + 0, 1, __ATOMIC_RELAXED,
                                          __HIP_MEMORY_SCOPE_AGENT);
            if (slot < 32) role = 0;
        } else if (xcd == 1) {
            slot = __hip_atomic_fetch_add(sync + 1, 1, __ATOMIC_RELAXED,
                                          __HIP_MEMORY_SCOPE_AGENT);
            if (slot < 32) role = 1;
        }
        rs[0] = role; rs[1] = slot;
    }
    __syncthreads();
    const int layer = rs[0];
    const int ut    = rs[1];
    if (layer < 0) return;

    const int rb = sync[2];   // run-unique tag base (uniform)
    const int mt = tid >> 6;
    const int l  = tid & 63;
    const int ul = l & 15;
    const int q  = l >> 4;
    const int KT = layer ? 32 : 24;
    const short8* ldsf = (const short8*)ldsw;

    // ---- stage weight slice into LDS ----
    {
        const unsigned short* wsrc = layer ? wp1 : wp0;
        for (int g = 0; g < 4; ++g) {
            const int4* src = (const int4*)(wsrc + (size_t)(g * 32 + ut) * KT * 512);
            int4* dst = ldsw + (size_t)g * KT * 64;
            for (int i = tid; i < KT * 64; i += 256) dst[i] = src[i];
        }
    }
    float bv[4];
    #pragma unroll
    for (int g = 0; g < 4; ++g) bv[g] = bs[layer * 2048 + g * HH + ut * 16 + ul];
    float cc[4] = {0.f, 0.f, 0.f, 0.f};
    __syncthreads();

    const int u = ut * 16 + ul;
    const int stg_w = mt * 256 + (ul >> 3) * 128 + (ul & 7);
    const int ring_sub = (ut >> 1) * 128 + ((2 * ut) & 3) * 32 + l;  // 16B units
    int fuel = 1 << 22;

    if (layer == 0) {
        for (int t = 0; t < HT; ++t) {
            f32x4 acc[4];
            #pragma unroll
            for (int g = 0; g < 4; ++g) {
                f32x4 a; a[0] = bv[g]; a[1] = bv[g]; a[2] = bv[g]; a[3] = bv[g];
                acc[g] = a;
            }
            // early-issue anti-dep f1m read; retired by the local pull's
            // vmcnt(0) (in-order); use pinned behind sched_barrier below.
            int adv = 0x7fffffff;
            if (t >= 4 && l < 32)
                asm volatile("global_load_dword %0, %1, off sc0 sc1"
                             : "=v"(adv) : "v"(f1m + mt * 32 + l) : "memory");

            // x half (no dependency)
            const short8* xa = (const short8*)xp + ((size_t)t * 4 + mt) * 8 * 64;
            #pragma unroll
            for (int kt = 0; kt < 8; ++kt) {
                short8 a = xa[kt * 64 + l];
                #pragma unroll
                for (int g = 0; g < 4; ++g)
                    acc[g] = __builtin_amdgcn_mfma_f32_16x16x32_bf16(
                        a, ldsf[(g * 24 + kt) * 64 + l], acc[g], 0, 0, 0);
            }
            if (t > 0) {
                short8 af[16];
                pull16_loc(h0loc + (size_t)(((t - 1) & 1) * 4 + mt) * 32768 +
                           (size_t)l * 32, rb + t - 1, af, fuel);
                #pragma unroll
                for (int kt = 0; kt < 16; ++kt) {
                    #pragma unroll
                    for (int g = 0; g < 4; ++g)
                        acc[g] = __builtin_amdgcn_mfma_f32_16x16x32_bf16(
                            af[kt], ldsf[(g * 24 + 8 + kt) * 64 + l], acc[g], 0, 0, 0);
                }
            }
            // ---- epilogue ----
            #pragma unroll
            for (int r = 0; r < 4; ++r) {
                int m = q * 4 + r;
                int b = mt * 16 + m;
                float iv = fsigmoid(acc[0][r]);
                float fv2 = fsigmoid(acc[1][r]);
                float gv = ftanh(acc[2][r]);
                float ov = fsigmoid(acc[3][r]);
                float c = fv2 * cc[r] + iv * gv;
                cc[r] = c;
                float h = ov * ftanh(c);
                stage_s[stg_w + m * 8] = f2bf(h);
                if (t == HT - 1) {
                    out[33554432 + b * 512 + u] = h;   // hidden, layer0
                    out[33619968 + b * 512 + u] = c;   // cell, layer0
                }
            }
            lds_fence();
            unsigned s0 = stage_s[tid * 4 + 0], s1 = stage_s[tid * 4 + 1];
            unsigned s2 = stage_s[tid * 4 + 2], s3 = stage_s[tid * 4 + 3];
            i32x4 pv;
            pv[0] = (int)(s0 | (s1 << 16));
            pv[1] = (int)(s2 | (s3 << 16));
            pv[2] = rb + t; pv[3] = 0;

            // anti-dep gate for h0mall slot reuse (t>=4 => pull ran => adv
            // retired; SB pins the compare after the pull's vmcnt).
            if (t >= 4) {
                __builtin_amdgcn_sched_barrier(0);
                if (__ballot(adv >= t - 3) != ~0ull) {
                    const int* ap = f1m + mt * 32 + (l & 31);
                    for (;;) {
                        int v2 = (l < 32) ? ld4m(ap) : 0x7fffffff;
                        if (__ballot(v2 >= t - 3) == ~0ull) break;
                        if (--fuel <= 0) break;
                        __builtin_amdgcn_s_sleep(1);
                    }
                }
            }
            // fire-and-forget tagged stores: local ring + MALL feed copy
            st_pair_loc(h0loc + ((size_t)((t & 1) * 4 + mt) * 2048 + ring_sub) * 16, pv);
            st_pair_mall(h0mall + ((size_t)((t & 3) * 4 + mt) * 2048 + ring_sub) * 16, pv);
        }
    } else {
        for (int t = 0; t < HT; ++t) {
            f32x4 acc[4];
            #pragma unroll
            for (int g = 0; g < 4; ++g) {
                f32x4 a; a[0] = bv[g]; a[1] = bv[g]; a[2] = bv[g]; a[3] = bv[g];
                acc[g] = a;
            }
            short8 af1[16];
            if (t > 0)
                pull16_loc(h1loc + (size_t)(((t - 1) & 1) * 4 + mt) * 32768 +
                           (size_t)l * 32, rb + t - 1, af1, fuel);

            // issue h0mall loads now (flight hidden under recurrent MFMAs)
            i32x4 vm[32];
            const char* mbase = h0mall + (size_t)((t & 3) * 4 + mt) * 32768 +
                                (size_t)l * 32;
            {
                const char* b = mbase;
                #pragma unroll
                for (int bi = 0; bi < 8; ++bi) {
                    asm volatile("global_load_dwordx4 %0, %1, off sc0 sc1"
                                 : "=v"(vm[bi * 4 + 0]) : "v"(b));
                    asm volatile("global_load_dwordx4 %0, %1, off offset:16 sc0 sc1"
                                 : "=v"(vm[bi * 4 + 1]) : "v"(b));
                    asm volatile("global_load_dwordx4 %0, %1, off offset:2048 sc0 sc1"
                                 : "=v"(vm[bi * 4 + 2]) : "v"(b));
                    asm volatile("global_load_dwordx4 %0, %1, off offset:2064 sc0 sc1"
                                 : "=v"(vm[bi * 4 + 3]) : "v"(b));
                    b += 4096;
                }
            }
            if (t > 0) {
                #pragma unroll
                for (int kt = 0; kt < 16; ++kt) {
                    #pragma unroll
                    for (int g = 0; g < 4; ++g)
                        acc[g] = __builtin_amdgcn_mfma_f32_16x16x32_bf16(
                            af1[kt], ldsf[(g * 32 + 16 + kt) * 64 + l], acc[g], 0, 0, 0);
                }
            }
            // h0 feed: validate tags (rule-#18 guarded), retry if early
            asm volatile("s_waitcnt vmcnt(0)" ::: "memory");
            __builtin_amdgcn_sched_barrier(0);
            short8 af0[16];
            {
                int ok = 1;
                #pragma unroll
                for (int i = 0; i < 32; ++i)
                    ok &= (vm[i][2] == rb + t) & (vm[i][3] == 0);
                if (__ballot(ok != 0) == ~0ull) {
                    #pragma unroll
                    for (int kt = 0; kt < 16; ++kt) {
                        union { int i4[4]; short8 s; } uu;
                        uu.i4[0] = vm[2 * kt][0];     uu.i4[1] = vm[2 * kt][1];
                        uu.i4[2] = vm[2 * kt + 1][0]; uu.i4[3] = vm[2 * kt + 1][1];
                        af0[kt] = uu.s;
                    }
                } else {
                    pull16_mall(mbase, rb + t, af0, fuel);
                }
            }
            #pragma unroll
            for (int kt = 0; kt < 16; ++kt) {
                #pragma unroll
                for (int g = 0; g < 4; ++g)
                    acc[g] = __builtin_amdgcn_mfma_f32_16x16x32_bf16(
                        af0[kt], ldsf[(g * 32 + kt) * 64 + l], acc[g], 0, 0, 0);
            }
            // ---- epilogue ----
            #pragma unroll
            for (int r = 0; r < 4; ++r) {
                int m = q * 4 + r;
                int b = mt * 16 + m;
                float iv = fsigmoid(acc[0][r]);
                float fv2 = fsigmoid(acc[1][r]);
                float gv = ftanh(acc[2][r]);
                float ov = fsigmoid(acc[3][r]);
                float c = fv2 * cc[r] + iv * gv;
                cc[r] = c;
                float h = ov * ftanh(c);
                stage_s[stg_w + m * 8] = f2bf(h);
                if (t == HT - 1) {
                    out[33554432 + 32768 + b * 512 + u] = h;   // hidden, layer1
                    out[33619968 + 32768 + b * 512 + u] = c;   // cell, layer1
                }
            }
            lds_fence();
            unsigned s0 = stage_s[tid * 4 + 0], s1 = stage_s[tid * 4 + 1];
            unsigned s2 = stage_s[tid * 4 + 2], s3 = stage_s[tid * 4 + 3];
            i32x4 pv;
            pv[0] = (int)(s0 | (s1 << 16));
            pv[1] = (int)(s2 | (s3 << 16));
            pv[2] = rb + t; pv[3] = 0;
            st_pair_loc(h1loc + ((size_t)((t & 1) * 4 + mt) * 2048 + ring_sub) * 16, pv);
            // progress flag (certifies h0mall slot t consumed — pull done
            // before this point by program order + its vmcnt). Fire & forget.
            if (l == 0)
                __hip_atomic_store(f1m + mt * 32 + ut, t + 1,
                                   __ATOMIC_RELAXED, __HIP_MEMORY_SCOPE_AGENT);
            // sequence output (plain cached stores, off critical path)
            {
                int lb = l >> 2, ch = l & 3;
                int b = mt * 16 + lb;
                const unsigned short* sp = stage_s + mt * 256 + (ch >> 1) * 128 +
                                           lb * 8 + (ch & 1) * 4;
                f32x4 o;
                o[0] = bf2f(sp[0]); o[1] = bf2f(sp[1]);
                o[2] = bf2f(sp[2]); o[3] = bf2f(sp[3]);
                *(f32x4*)&out[((size_t)b * HT + t) * HH + ut * 16 + ch * 4] = o;
            }
        }
    }
}

extern "C" void kernel_launch(void* const* d_in, const int* in_sizes, int n_in,
                              void* d_out, int out_size, void* d_ws, size_t ws_size,
                              hipStream_t stream) {
    const float* x    = (const float*)d_in[0];
    const float* Wih0 = (const float*)d_in[1];
    const float* Whh0 = (const float*)d_in[2];
    const float* bih0 = (const float*)d_in[3];
    const float* bhh0 = (const float*)d_in[4];
    const float* Wih1 = (const float*)d_in[5];
    const float* Whh1 = (const float*)d_in[6];
    const float* bih1 = (const float*)d_in[7];
    const float* bhh1 = (const float*)d_in[8];

    char* ws = (char*)d_ws;
    // ws layout (bytes), total 41,960,448:
    //   wp0:    0          .. 3,145,728
    //   wp1:    3,145,728  .. 7,340,032
    //   bs:     7,340,032  .. 7,356,416
    //   xp:     7,356,416  .. 40,910,848
    //   sync:   40,910,848 .. 40,911,872  (cnt[2], rb, f1m[128] @ +256B)
    //   h0loc:  40,911,872 .. 41,174,016  (2 slots x 128 KB tagged, XCD0 L2)
    //   h1loc:  41,174,016 .. 41,436,160  (2 slots x 128 KB tagged, XCD1 L2)
    //   h0mall: 41,436,160 .. 41,960,448  (4 slots x 128 KB tagged, MALL)
    unsigned short* wp0 = (unsigned short*)(ws + 0);
    unsigned short* wp1 = (unsigned short*)(ws + 3145728);
    float*          bsv = (float*)(ws + 7340032);
    unsigned short* xp  = (unsigned short*)(ws + 7356416);
    int*   sync         = (int*)(ws + 40910848);
    char*  h0loc        = ws + 40911872;
    char*  h1loc        = ws + 41174016;
    char*  h0mall       = ws + 41436160;
    float* out = (float*)d_out;

    pack_weights<<<2048, 256, 0, stream>>>(Wih0, Whh0, bih0, bhh0,
                                           Wih1, Whh1, bih1, bhh1, wp0, wp1, bsv);
    pack_x<<<dim3(64, 8, 4), 256, 0, stream>>>(x, xp);
    init_sync<<<1, 256, 0, stream>>>(sync);

    lstm_persist<<<256, 256, 0, stream>>>(wp0, wp1, bsv, xp,
                                          h0loc, h1loc, h0mall, sync, out);
}